// Round 2
// 594.073 us; speedup vs baseline: 1.2418x; 1.2418x over previous
//
#include <hip/hip_runtime.h>

typedef unsigned short u16;
typedef unsigned int u32;
typedef __bf16 bf16x8 __attribute__((ext_vector_type(8)));
typedef float f32x4 __attribute__((ext_vector_type(4)));

#define MFMA16(a,b,c) __builtin_amdgcn_mfma_f32_16x16x32_bf16((a),(b),(c),0,0,0)

__device__ __forceinline__ u16 f2bf(float x) {
  u32 u = __float_as_uint(x);
  u32 r = (u + 0x7fffu + ((u >> 16) & 1u)) >> 16;
  return (u16)r;
}

// branch-free erf-based GELU (A&S 7.1.26, |err| <= 1.5e-7)
__device__ __forceinline__ float gelu_f(float v) {
  float u = v * 0.70710678118654752f;
  float a = fabsf(u);
  float t = 1.f / (1.f + 0.3275911f * a);
  float p = t * (0.254829592f + t * (-0.284496736f + t * (1.421413741f +
            t * (-1.453152027f + t * 1.061405429f))));
  float e = __expf(-u * u);
  float er = 1.f - p * e;
  er = (u < 0.f) ? -er : er;
  return 0.5f * v * (1.f + er);
}

// ---------------- weight -> bf16 MFMA-fragment order ----------------
// Fragment f holds the B-operand tile (n-tile of 16, k-tile of 32) for
// mfma_f32_16x16x32_bf16: lane ln holds B[n = nt*16 + (ln&15)][k = kt*32 +
// (ln>>4)*8 + e], stored contiguously at wf[(f<<9) + (ln<<3) + e].
__global__ __launch_bounds__(256) void prep_weights(
    const float* __restrict__ qkv_w, const float* __restrict__ proj_w,
    const float* __restrict__ fc1_w, const float* __restrict__ fc2_w,
    u16* __restrict__ qkv_wf, u16* __restrict__ proj_wf,
    u16* __restrict__ fc1_wf, u16* __restrict__ fc2_wf) {
  int t0 = blockIdx.x * 256 + threadIdx.x;
  int stride = gridDim.x * 256;
  // qkv: f = ct*6 + kc, ct<36 (n over 576), kc<6 (k over 192)
  for (int i = t0; i < 36 * 6 * 512; i += stride) {
    int f = i >> 9, ln = (i >> 3) & 63, e = i & 7;
    int ct = f / 6, kc = f - ct * 6;
    int n = ct * 16 + (ln & 15), k = kc * 32 + (ln >> 4) * 8 + e;
    qkv_wf[i] = f2bf(qkv_w[k * 576 + n]);
  }
  // proj: f = ct*6 + kc, ct<12 (n over 192), kc<6
  for (int i = t0; i < 12 * 6 * 512; i += stride) {
    int f = i >> 9, ln = (i >> 3) & 63, e = i & 7;
    int ct = f / 6, kc = f - ct * 6;
    int n = ct * 16 + (ln & 15), k = kc * 32 + (ln >> 4) * 8 + e;
    proj_wf[i] = f2bf(proj_w[k * 192 + n]);
  }
  // fc1: f = ctg*6 + kc, ctg<48 (n over 768), kc<6 (k over 192)
  for (int i = t0; i < 48 * 6 * 512; i += stride) {
    int f = i >> 9, ln = (i >> 3) & 63, e = i & 7;
    int ctg = f / 6, kc = f - ctg * 6;
    int n = ctg * 16 + (ln & 15), k = kc * 32 + (ln >> 4) * 8 + e;
    fc1_wf[i] = f2bf(fc1_w[k * 768 + n]);
  }
  // fc2: f = g2*12 + ct, g2<24 (k over 768 in 32-steps), ct<12 (n over 192)
  for (int i = t0; i < 24 * 12 * 512; i += stride) {
    int f = i >> 9, ln = (i >> 3) & 63, e = i & 7;
    int g2 = f / 12, ct = f - g2 * 12;
    int n = ct * 16 + (ln & 15), k = g2 * 32 + (ln >> 4) * 8 + e;
    fc2_wf[i] = f2bf(fc2_w[k * 192 + n]);
  }
}

// ---------------- fused LN1(+shift/window gather) + QKV GEMM ----------------
__global__ __launch_bounds__(256) void qkv_ln_kernel(
    const float* __restrict__ x, const float* __restrict__ g,
    const float* __restrict__ bb,
    const u16* __restrict__ qkv_wf, const float* __restrict__ qkv_b,
    u16* __restrict__ qkvb, int rowbase, int wbase) {
  __shared__ __align__(16) u16 sA[128 * 200];
  const int tid = threadIdx.x;
  const int r0 = rowbase + blockIdx.x * 128;

  {
    int r = tid >> 1, half = tid & 1;
    int gr = r0 + r;
    int w = gr / 49, n = gr - w * 49;
    int b = w >> 6, wi = w & 63;
    int rr = n / 7, cc = n - rr * 7;
    int hh = (wi >> 3) * 7 + rr + 3; if (hh >= 56) hh -= 56;
    int ww = (wi & 7) * 7 + cc + 3; if (ww >= 56) ww -= 56;
    const float* src = x + ((size_t)b * 3136 + hh * 56 + ww) * 192 + half * 96;
    float s1 = 0.f, s2 = 0.f;
    #pragma unroll
    for (int i = 0; i < 24; i++) {
      float4 v = ((const float4*)src)[i];
      s1 += v.x + v.y + v.z + v.w;
      s2 += v.x * v.x + v.y * v.y + v.z * v.z + v.w * v.w;
    }
    s1 += __shfl_xor(s1, 1);
    s2 += __shfl_xor(s2, 1);
    float mu = s1 * (1.f / 192.f);
    float var = s2 * (1.f / 192.f) - mu * mu;
    float rs = rsqrtf(var + 1e-5f);
    u16* drow = sA + r * 200 + half * 96;
    #pragma unroll
    for (int i = 0; i < 24; i++) {
      float4 v = ((const float4*)src)[i];
      int c = half * 96 + i * 4;
      ushort4 o;
      o.x = f2bf((v.x - mu) * rs * g[c + 0] + bb[c + 0]);
      o.y = f2bf((v.y - mu) * rs * g[c + 1] + bb[c + 1]);
      o.z = f2bf((v.z - mu) * rs * g[c + 2] + bb[c + 2]);
      o.w = f2bf((v.w - mu) * rs * g[c + 3] + bb[c + 3]);
      *((ushort4*)(drow + i * 4)) = o;
    }
  }
  __syncthreads();

  const int wv = tid >> 6, ln = tid & 63, lrow = ln & 15, quad = ln >> 4;
  const int ln8 = ln << 3;

  u32 qkoff[8], voff[8];
  #pragma unroll
  for (int rt = 0; rt < 2; rt++) {
    #pragma unroll
    for (int reg = 0; reg < 4; reg++) {
      int grow = r0 + 32 * wv + 16 * rt + quad * 4 + reg;
      int w_ = grow / 49, n_ = grow - w_ * 49;
      u32 wb = (u32)(w_ - wbase) * 29568u;
      qkoff[rt * 4 + reg] = wb + (u32)n_ * 32u;
      voff[rt * 4 + reg] = wb + (u32)n_;
    }
  }

  for (int ct = 0; ct < 36; ct++) {
    f32x4 acc0 = (f32x4){0.f, 0.f, 0.f, 0.f};
    f32x4 acc1 = (f32x4){0.f, 0.f, 0.f, 0.f};
    #pragma unroll
    for (int kc = 0; kc < 6; kc++) {
      bf16x8 a0 = *(const bf16x8*)(sA + (32 * wv + lrow) * 200 + kc * 32 + quad * 8);
      bf16x8 a1 = *(const bf16x8*)(sA + (32 * wv + 16 + lrow) * 200 + kc * 32 + quad * 8);
      bf16x8 bw = *(const bf16x8*)(qkv_wf + ((ct * 6 + kc) << 9) + ln8);
      acc0 = MFMA16(a0, bw, acc0);
      acc1 = MFMA16(a1, bw, acc1);
    }
    int sec = ct / 12, ccc = ct - sec * 12;
    int head = ccc >> 1, d0 = (ccc & 1) * 16;
    int col = d0 + lrow;
    float bias = qkv_b[sec * 192 + head * 32 + col];
    u32 hoff = (u32)head * 4928u;
    if (sec < 2) {
      u32 coff = hoff + (u32)sec * 1568u + (u32)col;
      #pragma unroll
      for (int reg = 0; reg < 4; reg++) {
        qkvb[qkoff[reg] + coff] = f2bf(acc0[reg] + bias);
        qkvb[qkoff[4 + reg] + coff] = f2bf(acc1[reg] + bias);
      }
    } else {
      u32 coff = hoff + 3136u + (u32)col * 56u;
      #pragma unroll
      for (int reg = 0; reg < 4; reg++) {
        qkvb[voff[reg] + coff] = f2bf(acc0[reg] + bias);
        qkvb[voff[4 + reg] + coff] = f2bf(acc1[reg] + bias);
      }
    }
  }
}

// ---------------- window attention: 1 block/window, 1 wave/head ----------------
__global__ __launch_bounds__(384) void attn2_kernel(
    const u16* __restrict__ qkvb, u16* __restrict__ attnout, int wbase) {
  __shared__ __align__(16) u16 sP[6 * 64 * 72];
  const int tid = threadIdx.x;
  const int wv = tid >> 6;
  const int ln = tid & 63;
  const int lrow = ln & 15;
  const int quad = ln >> 4;
  const int wl = blockIdx.x;
  const int w = wbase + wl;
  const int wi = w & 63;
  const int wr = wi >> 3, wc = wi & 7;
  const u16* base = qkvb + (size_t)(wl * 6 + wv) * 4928;
  u16* sPw = sP + wv * (64 * 72);
  const f32x4 zero4 = {0.f, 0.f, 0.f, 0.f};

  bf16x8 kf[4];
  #pragma unroll
  for (int rt = 0; rt < 4; rt++)
    kf[rt] = *(const bf16x8*)(base + 1568 + (16 * rt + lrow) * 32 + quad * 8);
  f32x4 S[4][4];
  #pragma unroll
  for (int ct = 0; ct < 4; ct++) {
    bf16x8 qf = *(const bf16x8*)(base + (16 * ct + lrow) * 32 + quad * 8);
    #pragma unroll
    for (int rt = 0; rt < 4; rt++)
      S[rt][ct] = MFMA16(kf[rt], qf, zero4);
  }

  int hbn[4], wbn[4];
  #pragma unroll
  for (int ct = 0; ct < 4; ct++) {
    int n = 16 * ct + lrow;
    int rn = (n * 9363) >> 16;
    int cn = n - 7 * rn;
    hbn[ct] = (wr < 7) ? 0 : ((rn >= 4) ? 2 : 1);
    wbn[ct] = (wc < 7) ? 0 : ((cn >= 4) ? 2 : 1);
  }

  const float scale = 0.17677669529663687f;
  float mx[4] = {-1e30f, -1e30f, -1e30f, -1e30f};
  #pragma unroll
  for (int rt = 0; rt < 4; rt++) {
    #pragma unroll
    for (int reg = 0; reg < 4; reg++) {
      int m = 16 * rt + quad * 4 + reg;
      int rm = (m * 9363) >> 16;
      int cm = m - 7 * rm;
      int hbm = (wr < 7) ? 0 : ((rm >= 4) ? 2 : 1);
      int wbm = (wc < 7) ? 0 : ((cm >= 4) ? 2 : 1);
      bool padm = (m >= 49);
      #pragma unroll
      for (int ct = 0; ct < 4; ct++) {
        float sv = S[rt][ct][reg] * scale +
                   (((hbm != hbn[ct]) || (wbm != wbn[ct])) ? -100.f : 0.f);
        sv = padm ? -1e30f : sv;
        S[rt][ct][reg] = sv;
        mx[ct] = fmaxf(mx[ct], sv);
      }
    }
  }
  #pragma unroll
  for (int ct = 0; ct < 4; ct++) {
    mx[ct] = fmaxf(mx[ct], __shfl_xor(mx[ct], 16));
    mx[ct] = fmaxf(mx[ct], __shfl_xor(mx[ct], 32));
  }
  float sum[4] = {0.f, 0.f, 0.f, 0.f};
  #pragma unroll
  for (int rt = 0; rt < 4; rt++)
    #pragma unroll
    for (int reg = 0; reg < 4; reg++)
      #pragma unroll
      for (int ct = 0; ct < 4; ct++) {
        float e = __expf(S[rt][ct][reg] - mx[ct]);
        S[rt][ct][reg] = e;
        sum[ct] += e;
      }
  float inv[4];
  #pragma unroll
  for (int ct = 0; ct < 4; ct++) {
    sum[ct] += __shfl_xor(sum[ct], 16);
    sum[ct] += __shfl_xor(sum[ct], 32);
    inv[ct] = 1.f / sum[ct];
  }

  #pragma unroll
  for (int rt = 0; rt < 4; rt++) {
    #pragma unroll
    for (int ct = 0; ct < 4; ct++) {
      ushort4 o;
      o.x = f2bf(S[rt][ct][0] * inv[ct]);
      o.y = f2bf(S[rt][ct][1] * inv[ct]);
      o.z = f2bf(S[rt][ct][2] * inv[ct]);
      o.w = f2bf(S[rt][ct][3] * inv[ct]);
      *((ushort4*)(sPw + (16 * ct + lrow) * 72 + 16 * rt + quad * 4)) = o;
    }
  }

  f32x4 accO[4][2];
  #pragma unroll
  for (int rt = 0; rt < 4; rt++)
    #pragma unroll
    for (int cd = 0; cd < 2; cd++) accO[rt][cd] = zero4;
  #pragma unroll
  for (int kc = 0; kc < 2; kc++) {
    bf16x8 vf[2];
    #pragma unroll
    for (int cd = 0; cd < 2; cd++)
      vf[cd] = *(const bf16x8*)(base + 3136 + (16 * cd + lrow) * 56 + kc * 32 + quad * 8);
    #pragma unroll
    for (int rt = 0; rt < 4; rt++) {
      bf16x8 af = *(const bf16x8*)(sPw + (16 * rt + lrow) * 72 + kc * 32 + quad * 8);
      #pragma unroll
      for (int cd = 0; cd < 2; cd++)
        accO[rt][cd] = MFMA16(af, vf[cd], accO[rt][cd]);
    }
  }

  #pragma unroll
  for (int rt = 0; rt < 4; rt++) {
    #pragma unroll
    for (int reg = 0; reg < 4; reg++) {
      int n = 16 * rt + quad * 4 + reg;
      if (n < 49) {
        #pragma unroll
        for (int cd = 0; cd < 2; cd++)
          attnout[(size_t)(w * 49 + n) * 192 + wv * 32 + 16 * cd + lrow] =
              f2bf(accO[rt][cd][reg]);
      }
    }
  }
}

// ---------------- proj gemm + reverse partition/roll scatter ----------------
__global__ __launch_bounds__(256) void proj_kernel(
    const u16* __restrict__ attnout, const u16* __restrict__ proj_wf,
    const float* __restrict__ proj_b, float* __restrict__ out) {
  __shared__ __align__(16) u16 sA[128 * 200];
  const int tid = threadIdx.x;
  const int r0 = blockIdx.x * 128;
  {
    const u32* ag = (const u32*)(attnout + (size_t)r0 * 192);
    u32* d = (u32*)sA;
    for (int i = tid; i < 128 * 96; i += 256) {
      int r = i / 96, c = i - r * 96;
      d[r * 100 + c] = ag[i];
    }
  }
  __syncthreads();
  const int wv = tid >> 6, ln = tid & 63, lrow = ln & 15, quad = ln >> 4;
  const int ln8 = ln << 3;
  f32x4 acc[2][12];
  #pragma unroll
  for (int rt = 0; rt < 2; rt++)
    #pragma unroll
    for (int t = 0; t < 12; t++) acc[rt][t] = (f32x4){0.f, 0.f, 0.f, 0.f};
  #pragma unroll
  for (int kc = 0; kc < 6; kc++) {
    bf16x8 a0 = *(const bf16x8*)(sA + (32 * wv + lrow) * 200 + kc * 32 + quad * 8);
    bf16x8 a1 = *(const bf16x8*)(sA + (32 * wv + 16 + lrow) * 200 + kc * 32 + quad * 8);
    #pragma unroll
    for (int ct = 0; ct < 12; ct++) {
      bf16x8 bf_ = *(const bf16x8*)(proj_wf + ((ct * 6 + kc) << 9) + ln8);
      acc[0][ct] = MFMA16(a0, bf_, acc[0][ct]);
      acc[1][ct] = MFMA16(a1, bf_, acc[1][ct]);
    }
  }
  #pragma unroll
  for (int rt = 0; rt < 2; rt++) {
    #pragma unroll
    for (int r = 0; r < 4; r++) {
      int gr = r0 + 32 * wv + rt * 16 + quad * 4 + r;
      int w = gr / 49, n = gr - w * 49;
      int b = w >> 6, wi = w & 63;
      int hh = (wi >> 3) * 7 + n / 7 + 3; if (hh >= 56) hh -= 56;
      int ww = (wi & 7) * 7 + (n - (n / 7) * 7) + 3; if (ww >= 56) ww -= 56;
      float* orow = out + ((size_t)b * 3136 + hh * 56 + ww) * 192;
      #pragma unroll
      for (int ct = 0; ct < 12; ct++) {
        int col = ct * 16 + lrow;
        orow[col] = acc[rt][ct][r] + proj_b[col];
      }
    }
  }
}

// ---------------- fused LN2 + MLP ----------------
// 512 threads, 128 rows/block. Waves: rg = wv>>1 (row group of 32), cv = wv&1
// (column half). Per-wave acc: FC2 out 2x6 f32x4 (48 VGPR), FC1 transient
// 2x2 (16 VGPR). Hidden tile sT[128][64] bf16 shared, XOR-swizzled
// (byte ^= ((row>>1)&7)<<4) for conflict-free b128 reads. Weights read from
// global in fragment order (coalesced 16B/lane). LDS 67.6 KB -> 2 blk/CU
// -> 4 waves/SIMD.
__global__ __launch_bounds__(512, 4) void mlp_kernel(
    const float* __restrict__ xr, const float* __restrict__ g,
    const float* __restrict__ bb,
    const u16* __restrict__ fc1_wf, const float* __restrict__ fc1_b,
    const u16* __restrict__ fc2_wf, const float* __restrict__ fc2_b,
    float* __restrict__ out) {
  __shared__ __align__(16) u16 sA[128 * 200];
  __shared__ __align__(16) u16 sT[128 * 64];
  const int tid = threadIdx.x;
  const size_t r0 = (size_t)blockIdx.x * 128;

  // LN2: 4 threads per row
  {
    int r = tid >> 2, q4 = tid & 3;
    const float* src = xr + (r0 + r) * 192 + q4 * 48;
    float s1 = 0.f, s2 = 0.f;
    #pragma unroll
    for (int i = 0; i < 12; i++) {
      float4 v = ((const float4*)src)[i];
      s1 += v.x + v.y + v.z + v.w;
      s2 += v.x * v.x + v.y * v.y + v.z * v.z + v.w * v.w;
    }
    s1 += __shfl_xor(s1, 1);
    s2 += __shfl_xor(s2, 1);
    s1 += __shfl_xor(s1, 2);
    s2 += __shfl_xor(s2, 2);
    float mu = s1 * (1.f / 192.f);
    float var = s2 * (1.f / 192.f) - mu * mu;
    float rs = rsqrtf(var + 1e-5f);
    u16* drow = sA + r * 200 + q4 * 48;
    #pragma unroll
    for (int i = 0; i < 12; i++) {
      float4 v = ((const float4*)src)[i];
      int c = q4 * 48 + i * 4;
      ushort4 o;
      o.x = f2bf((v.x - mu) * rs * g[c + 0] + bb[c + 0]);
      o.y = f2bf((v.y - mu) * rs * g[c + 1] + bb[c + 1]);
      o.z = f2bf((v.z - mu) * rs * g[c + 2] + bb[c + 2]);
      o.w = f2bf((v.w - mu) * rs * g[c + 3] + bb[c + 3]);
      *((ushort4*)(drow + i * 4)) = o;
    }
  }
  __syncthreads();

  const int wv = tid >> 6, ln = tid & 63, lrow = ln & 15, quad = ln >> 4;
  const int rg = wv >> 1, cv = wv & 1;
  const int ln8 = ln << 3;

  f32x4 accO[2][6];
  #pragma unroll
  for (int rt = 0; rt < 2; rt++)
    #pragma unroll
    for (int t = 0; t < 6; t++) accO[rt][t] = (f32x4){0.f, 0.f, 0.f, 0.f};

  for (int ch = 0; ch < 12; ch++) {
    // FC1: hidden cols [ch*64 + cv*32, +32) for rows [32rg, +32)
    f32x4 accT[2][2];
    #pragma unroll
    for (int rt = 0; rt < 2; rt++)
      #pragma unroll
      for (int t = 0; t < 2; t++) accT[rt][t] = (f32x4){0.f, 0.f, 0.f, 0.f};
    #pragma unroll
    for (int kc = 0; kc < 6; kc++) {
      bf16x8 a0 = *(const bf16x8*)(sA + (32 * rg + lrow) * 200 + kc * 32 + quad * 8);
      bf16x8 a1 = *(const bf16x8*)(sA + (32 * rg + 16 + lrow) * 200 + kc * 32 + quad * 8);
      #pragma unroll
      for (int c2 = 0; c2 < 2; c2++) {
        bf16x8 b = *(const bf16x8*)(fc1_wf +
            (((ch * 4 + cv * 2 + c2) * 6 + kc) << 9) + ln8);
        accT[0][c2] = MFMA16(a0, b, accT[0][c2]);
        accT[1][c2] = MFMA16(a1, b, accT[1][c2]);
      }
    }
    // GELU -> swizzled sT
    #pragma unroll
    for (int rt = 0; rt < 2; rt++) {
      #pragma unroll
      for (int c2 = 0; c2 < 2; c2++) {
        int col = cv * 32 + c2 * 16 + lrow;
        float bias = fc1_b[ch * 64 + col];
        #pragma unroll
        for (int r = 0; r < 4; r++) {
          int row = 32 * rg + rt * 16 + quad * 4 + r;
          float v = accT[rt][c2][r] + bias;
          int byt = (row * 128 + col * 2) ^ (((row >> 1) & 7) << 4);
          *(u16*)((char*)sT + byt) = f2bf(gelu_f(v));
        }
      }
    }
    __syncthreads();
    // FC2: A = sT rows [32rg,+32) x k=64; B cols [cv*96, +96)
    #pragma unroll
    for (int kc2 = 0; kc2 < 2; kc2++) {
      int row0 = 32 * rg + lrow;
      int byt0 = (row0 * 128 + kc2 * 64 + quad * 16) ^ (((row0 >> 1) & 7) << 4);
      bf16x8 a0 = *(const bf16x8*)((const char*)sT + byt0);
      bf16x8 a1 = *(const bf16x8*)((const char*)sT + byt0 + 2048);
      #pragma unroll
      for (int ct = 0; ct < 6; ct++) {
        bf16x8 b = *(const bf16x8*)(fc2_wf +
            (((ch * 2 + kc2) * 12 + cv * 6 + ct) << 9) + ln8);
        accO[0][ct] = MFMA16(a0, b, accO[0][ct]);
        accO[1][ct] = MFMA16(a1, b, accO[1][ct]);
      }
    }
    __syncthreads();
  }

  #pragma unroll
  for (int rt = 0; rt < 2; rt++) {
    #pragma unroll
    for (int r = 0; r < 4; r++) {
      float* orow = out + (r0 + 32 * rg + rt * 16 + quad * 4 + r) * 192 + cv * 96;
      #pragma unroll
      for (int ct = 0; ct < 6; ct++) {
        int col = ct * 16 + lrow;
        orow[col] = orow[col] + accO[rt][ct][r] + fc2_b[cv * 96 + col];
      }
    }
  }
}

extern "C" void kernel_launch(void* const* d_in, const int* in_sizes, int n_in,
                              void* d_out, int out_size, void* d_ws, size_t ws_size,
                              hipStream_t stream) {
  const float* x      = (const float*)d_in[0];
  const float* qkv_w  = (const float*)d_in[1];
  const float* qkv_b  = (const float*)d_in[2];
  const float* proj_w = (const float*)d_in[3];
  const float* proj_b = (const float*)d_in[4];
  const float* n1_g   = (const float*)d_in[5];
  const float* n1_b   = (const float*)d_in[6];
  const float* n2_g   = (const float*)d_in[7];
  const float* n2_b   = (const float*)d_in[8];
  const float* fc1_w  = (const float*)d_in[9];
  const float* fc1_b  = (const float*)d_in[10];
  const float* fc2_w  = (const float*)d_in[11];
  const float* fc2_b  = (const float*)d_in[12];
  float* out = (float*)d_out;
  char* ws = (char*)d_ws;

  // workspace layout (bytes)
  u16* qkvb    = (u16*)(ws + 0);            // 1024*6*4928*2 = 60,555,264
  u16* attnout = (u16*)(ws + 60555264);     // 38,535,168 -> ends 99,090,432
  u16* qkv_wf  = (u16*)(ws + 99090432);     // 221,184
  u16* proj_wf = (u16*)(ws + 99311616);     // 73,728
  u16* fc1_wf  = (u16*)(ws + 99385344);     // 294,912
  u16* fc2_wf  = (u16*)(ws + 99680256);     // 294,912 -> ends 99,975,168

  prep_weights<<<256, 256, 0, stream>>>(qkv_w, proj_w, fc1_w, fc2_w,
                                        qkv_wf, proj_wf, fc1_wf, fc2_wf);
  for (int hf = 0; hf < 2; hf++) {
    qkv_ln_kernel<<<392, 256, 0, stream>>>(x, n1_g, n1_b, qkv_wf, qkv_b,
                                           qkvb, hf * 50176, hf * 1024);
    attn2_kernel<<<1024, 384, 0, stream>>>(qkvb, attnout, hf * 1024);
  }
  proj_kernel<<<784, 256, 0, stream>>>(attnout, proj_wf, proj_b, out);
  mlp_kernel<<<784, 512, 0, stream>>>(out, n2_g, n2_b,
                                      fc1_wf, fc1_b, fc2_wf, fc2_b, out);
}

// Round 3
// 588.806 us; speedup vs baseline: 1.2529x; 1.0089x over previous
//
#include <hip/hip_runtime.h>

typedef unsigned short u16;
typedef unsigned int u32;
typedef __bf16 bf16x8 __attribute__((ext_vector_type(8)));
typedef float f32x4 __attribute__((ext_vector_type(4)));

#define MFMA16(a,b,c) __builtin_amdgcn_mfma_f32_16x16x32_bf16((a),(b),(c),0,0,0)

__device__ __forceinline__ u16 f2bf(float x) {
  u32 u = __float_as_uint(x);
  u32 r = (u + 0x7fffu + ((u >> 16) & 1u)) >> 16;
  return (u16)r;
}

// branch-free erf-based GELU (A&S 7.1.26, |err| <= 1.5e-7)
__device__ __forceinline__ float gelu_f(float v) {
  float u = v * 0.70710678118654752f;
  float a = fabsf(u);
  float t = 1.f / (1.f + 0.3275911f * a);
  float p = t * (0.254829592f + t * (-0.284496736f + t * (1.421413741f +
            t * (-1.453152027f + t * 1.061405429f))));
  float e = __expf(-u * u);
  float er = 1.f - p * e;
  er = (u < 0.f) ? -er : er;
  return 0.5f * v * (1.f + er);
}

// ---------------- weight -> bf16 MFMA-fragment order ----------------
// Fragment f holds the B-operand tile (n-tile of 16, k-tile of 32) for
// mfma_f32_16x16x32_bf16: lane ln holds B[n = nt*16 + (ln&15)][k = kt*32 +
// (ln>>4)*8 + e], stored contiguously at wf[(f<<9) + (ln<<3) + e].
__global__ __launch_bounds__(256) void prep_weights(
    const float* __restrict__ qkv_w, const float* __restrict__ proj_w,
    const float* __restrict__ fc1_w, const float* __restrict__ fc2_w,
    u16* __restrict__ qkv_wf, u16* __restrict__ proj_wf,
    u16* __restrict__ fc1_wf, u16* __restrict__ fc2_wf) {
  int t0 = blockIdx.x * 256 + threadIdx.x;
  int stride = gridDim.x * 256;
  // qkv: f = ct*6 + kc, ct<36 (n over 576), kc<6 (k over 192)
  for (int i = t0; i < 36 * 6 * 512; i += stride) {
    int f = i >> 9, ln = (i >> 3) & 63, e = i & 7;
    int ct = f / 6, kc = f - ct * 6;
    int n = ct * 16 + (ln & 15), k = kc * 32 + (ln >> 4) * 8 + e;
    qkv_wf[i] = f2bf(qkv_w[k * 576 + n]);
  }
  // proj: f = ct*6 + kc, ct<12 (n over 192), kc<6
  for (int i = t0; i < 12 * 6 * 512; i += stride) {
    int f = i >> 9, ln = (i >> 3) & 63, e = i & 7;
    int ct = f / 6, kc = f - ct * 6;
    int n = ct * 16 + (ln & 15), k = kc * 32 + (ln >> 4) * 8 + e;
    proj_wf[i] = f2bf(proj_w[k * 192 + n]);
  }
  // fc1: f = ctg*6 + kc, ctg<48 (n over 768), kc<6 (k over 192)
  for (int i = t0; i < 48 * 6 * 512; i += stride) {
    int f = i >> 9, ln = (i >> 3) & 63, e = i & 7;
    int ctg = f / 6, kc = f - ctg * 6;
    int n = ctg * 16 + (ln & 15), k = kc * 32 + (ln >> 4) * 8 + e;
    fc1_wf[i] = f2bf(fc1_w[k * 768 + n]);
  }
  // fc2: f = g2*12 + ct, g2<24 (k over 768 in 32-steps), ct<12 (n over 192)
  for (int i = t0; i < 24 * 12 * 512; i += stride) {
    int f = i >> 9, ln = (i >> 3) & 63, e = i & 7;
    int g2 = f / 12, ct = f - g2 * 12;
    int n = ct * 16 + (ln & 15), k = g2 * 32 + (ln >> 4) * 8 + e;
    fc2_wf[i] = f2bf(fc2_w[k * 192 + n]);
  }
}

// ---------------- fused LN1(+shift/window gather) + QKV GEMM ----------------
__global__ __launch_bounds__(256) void qkv_ln_kernel(
    const float* __restrict__ x, const float* __restrict__ g,
    const float* __restrict__ bb,
    const u16* __restrict__ qkv_wf, const float* __restrict__ qkv_b,
    u16* __restrict__ qkvb, int rowbase, int wbase) {
  __shared__ __align__(16) u16 sA[128 * 200];
  const int tid = threadIdx.x;
  const int r0 = rowbase + blockIdx.x * 128;

  {
    int r = tid >> 1, half = tid & 1;
    int gr = r0 + r;
    int w = gr / 49, n = gr - w * 49;
    int b = w >> 6, wi = w & 63;
    int rr = n / 7, cc = n - rr * 7;
    int hh = (wi >> 3) * 7 + rr + 3; if (hh >= 56) hh -= 56;
    int ww = (wi & 7) * 7 + cc + 3; if (ww >= 56) ww -= 56;
    const float* src = x + ((size_t)b * 3136 + hh * 56 + ww) * 192 + half * 96;
    float s1 = 0.f, s2 = 0.f;
    #pragma unroll
    for (int i = 0; i < 24; i++) {
      float4 v = ((const float4*)src)[i];
      s1 += v.x + v.y + v.z + v.w;
      s2 += v.x * v.x + v.y * v.y + v.z * v.z + v.w * v.w;
    }
    s1 += __shfl_xor(s1, 1);
    s2 += __shfl_xor(s2, 1);
    float mu = s1 * (1.f / 192.f);
    float var = s2 * (1.f / 192.f) - mu * mu;
    float rs = rsqrtf(var + 1e-5f);
    u16* drow = sA + r * 200 + half * 96;
    #pragma unroll
    for (int i = 0; i < 24; i++) {
      float4 v = ((const float4*)src)[i];
      int c = half * 96 + i * 4;
      ushort4 o;
      o.x = f2bf((v.x - mu) * rs * g[c + 0] + bb[c + 0]);
      o.y = f2bf((v.y - mu) * rs * g[c + 1] + bb[c + 1]);
      o.z = f2bf((v.z - mu) * rs * g[c + 2] + bb[c + 2]);
      o.w = f2bf((v.w - mu) * rs * g[c + 3] + bb[c + 3]);
      *((ushort4*)(drow + i * 4)) = o;
    }
  }
  __syncthreads();

  const int wv = tid >> 6, ln = tid & 63, lrow = ln & 15, quad = ln >> 4;
  const int ln8 = ln << 3;

  u32 qkoff[8], voff[8];
  #pragma unroll
  for (int rt = 0; rt < 2; rt++) {
    #pragma unroll
    for (int reg = 0; reg < 4; reg++) {
      int grow = r0 + 32 * wv + 16 * rt + quad * 4 + reg;
      int w_ = grow / 49, n_ = grow - w_ * 49;
      u32 wb = (u32)(w_ - wbase) * 29568u;
      qkoff[rt * 4 + reg] = wb + (u32)n_ * 32u;
      voff[rt * 4 + reg] = wb + (u32)n_;
    }
  }

  for (int ct = 0; ct < 36; ct++) {
    f32x4 acc0 = (f32x4){0.f, 0.f, 0.f, 0.f};
    f32x4 acc1 = (f32x4){0.f, 0.f, 0.f, 0.f};
    #pragma unroll
    for (int kc = 0; kc < 6; kc++) {
      bf16x8 a0 = *(const bf16x8*)(sA + (32 * wv + lrow) * 200 + kc * 32 + quad * 8);
      bf16x8 a1 = *(const bf16x8*)(sA + (32 * wv + 16 + lrow) * 200 + kc * 32 + quad * 8);
      bf16x8 bw = *(const bf16x8*)(qkv_wf + ((ct * 6 + kc) << 9) + ln8);
      acc0 = MFMA16(a0, bw, acc0);
      acc1 = MFMA16(a1, bw, acc1);
    }
    int sec = ct / 12, ccc = ct - sec * 12;
    int head = ccc >> 1, d0 = (ccc & 1) * 16;
    int col = d0 + lrow;
    float bias = qkv_b[sec * 192 + head * 32 + col];
    u32 hoff = (u32)head * 4928u;
    if (sec < 2) {
      u32 coff = hoff + (u32)sec * 1568u + (u32)col;
      #pragma unroll
      for (int reg = 0; reg < 4; reg++) {
        qkvb[qkoff[reg] + coff] = f2bf(acc0[reg] + bias);
        qkvb[qkoff[4 + reg] + coff] = f2bf(acc1[reg] + bias);
      }
    } else {
      u32 coff = hoff + 3136u + (u32)col * 56u;
      #pragma unroll
      for (int reg = 0; reg < 4; reg++) {
        qkvb[voff[reg] + coff] = f2bf(acc0[reg] + bias);
        qkvb[voff[4 + reg] + coff] = f2bf(acc1[reg] + bias);
      }
    }
  }
}

// ---------------- window attention: 1 block/window, 1 wave/head ----------------
__global__ __launch_bounds__(384) void attn2_kernel(
    const u16* __restrict__ qkvb, u16* __restrict__ attnout, int wbase) {
  __shared__ __align__(16) u16 sP[6 * 64 * 72];
  const int tid = threadIdx.x;
  const int wv = tid >> 6;
  const int ln = tid & 63;
  const int lrow = ln & 15;
  const int quad = ln >> 4;
  const int wl = blockIdx.x;
  const int w = wbase + wl;
  const int wi = w & 63;
  const int wr = wi >> 3, wc = wi & 7;
  const u16* base = qkvb + (size_t)(wl * 6 + wv) * 4928;
  u16* sPw = sP + wv * (64 * 72);
  const f32x4 zero4 = {0.f, 0.f, 0.f, 0.f};

  bf16x8 kf[4];
  #pragma unroll
  for (int rt = 0; rt < 4; rt++)
    kf[rt] = *(const bf16x8*)(base + 1568 + (16 * rt + lrow) * 32 + quad * 8);
  f32x4 S[4][4];
  #pragma unroll
  for (int ct = 0; ct < 4; ct++) {
    bf16x8 qf = *(const bf16x8*)(base + (16 * ct + lrow) * 32 + quad * 8);
    #pragma unroll
    for (int rt = 0; rt < 4; rt++)
      S[rt][ct] = MFMA16(kf[rt], qf, zero4);
  }

  int hbn[4], wbn[4];
  #pragma unroll
  for (int ct = 0; ct < 4; ct++) {
    int n = 16 * ct + lrow;
    int rn = (n * 9363) >> 16;
    int cn = n - 7 * rn;
    hbn[ct] = (wr < 7) ? 0 : ((rn >= 4) ? 2 : 1);
    wbn[ct] = (wc < 7) ? 0 : ((cn >= 4) ? 2 : 1);
  }

  const float scale = 0.17677669529663687f;
  float mx[4] = {-1e30f, -1e30f, -1e30f, -1e30f};
  #pragma unroll
  for (int rt = 0; rt < 4; rt++) {
    #pragma unroll
    for (int reg = 0; reg < 4; reg++) {
      int m = 16 * rt + quad * 4 + reg;
      int rm = (m * 9363) >> 16;
      int cm = m - 7 * rm;
      int hbm = (wr < 7) ? 0 : ((rm >= 4) ? 2 : 1);
      int wbm = (wc < 7) ? 0 : ((cm >= 4) ? 2 : 1);
      bool padm = (m >= 49);
      #pragma unroll
      for (int ct = 0; ct < 4; ct++) {
        float sv = S[rt][ct][reg] * scale +
                   (((hbm != hbn[ct]) || (wbm != wbn[ct])) ? -100.f : 0.f);
        sv = padm ? -1e30f : sv;
        S[rt][ct][reg] = sv;
        mx[ct] = fmaxf(mx[ct], sv);
      }
    }
  }
  #pragma unroll
  for (int ct = 0; ct < 4; ct++) {
    mx[ct] = fmaxf(mx[ct], __shfl_xor(mx[ct], 16));
    mx[ct] = fmaxf(mx[ct], __shfl_xor(mx[ct], 32));
  }
  float sum[4] = {0.f, 0.f, 0.f, 0.f};
  #pragma unroll
  for (int rt = 0; rt < 4; rt++)
    #pragma unroll
    for (int reg = 0; reg < 4; reg++)
      #pragma unroll
      for (int ct = 0; ct < 4; ct++) {
        float e = __expf(S[rt][ct][reg] - mx[ct]);
        S[rt][ct][reg] = e;
        sum[ct] += e;
      }
  float inv[4];
  #pragma unroll
  for (int ct = 0; ct < 4; ct++) {
    sum[ct] += __shfl_xor(sum[ct], 16);
    sum[ct] += __shfl_xor(sum[ct], 32);
    inv[ct] = 1.f / sum[ct];
  }

  #pragma unroll
  for (int rt = 0; rt < 4; rt++) {
    #pragma unroll
    for (int ct = 0; ct < 4; ct++) {
      ushort4 o;
      o.x = f2bf(S[rt][ct][0] * inv[ct]);
      o.y = f2bf(S[rt][ct][1] * inv[ct]);
      o.z = f2bf(S[rt][ct][2] * inv[ct]);
      o.w = f2bf(S[rt][ct][3] * inv[ct]);
      *((ushort4*)(sPw + (16 * ct + lrow) * 72 + 16 * rt + quad * 4)) = o;
    }
  }

  f32x4 accO[4][2];
  #pragma unroll
  for (int rt = 0; rt < 4; rt++)
    #pragma unroll
    for (int cd = 0; cd < 2; cd++) accO[rt][cd] = zero4;
  #pragma unroll
  for (int kc = 0; kc < 2; kc++) {
    bf16x8 vf[2];
    #pragma unroll
    for (int cd = 0; cd < 2; cd++)
      vf[cd] = *(const bf16x8*)(base + 3136 + (16 * cd + lrow) * 56 + kc * 32 + quad * 8);
    #pragma unroll
    for (int rt = 0; rt < 4; rt++) {
      bf16x8 af = *(const bf16x8*)(sPw + (16 * rt + lrow) * 72 + kc * 32 + quad * 8);
      #pragma unroll
      for (int cd = 0; cd < 2; cd++)
        accO[rt][cd] = MFMA16(af, vf[cd], accO[rt][cd]);
    }
  }

  #pragma unroll
  for (int rt = 0; rt < 4; rt++) {
    #pragma unroll
    for (int reg = 0; reg < 4; reg++) {
      int n = 16 * rt + quad * 4 + reg;
      if (n < 49) {
        #pragma unroll
        for (int cd = 0; cd < 2; cd++)
          attnout[(size_t)(w * 49 + n) * 192 + wv * 32 + 16 * cd + lrow] =
              f2bf(accO[rt][cd][reg]);
      }
    }
  }
}

// ---------------- fused proj GEMM + LN2 + MLP + residual + scatter ----------------
// 256 threads, 64 rows/block, each wave owns 16 rows end-to-end. The proj
// MFMA D-layout (row = quad*4+reg, col = ct*16+lrow) is identical to the
// FC2 output layout, so the xr residual stays in 48 VGPRs; LN2 is done in
// registers (shfl over lrow bits). Hidden tile is wave-private ping-pong
// LDS (no barriers anywhere). Weights stream from L2 in fragment order.
__global__ __launch_bounds__(256, 2) void projmlp_kernel(
    const u16* __restrict__ attnout, const u16* __restrict__ proj_wf,
    const float* __restrict__ proj_b,
    const float* __restrict__ g, const float* __restrict__ bb,
    const u16* __restrict__ fc1_wf, const float* __restrict__ fc1_b,
    const u16* __restrict__ fc2_wf, const float* __restrict__ fc2_b,
    float* __restrict__ out) {
  __shared__ __align__(16) u16 sX[4 * 16 * 200];
  __shared__ __align__(16) u16 sT[4 * 2 * 16 * 72];
  const int tid = threadIdx.x;
  const int wv = tid >> 6, ln = tid & 63, lrow = ln & 15, quad = ln >> 4;
  const int ln8 = ln << 3;
  const int r0 = blockIdx.x * 64 + 16 * wv;   // wave's first row (window order)
  u16* sXw = sX + wv * (16 * 200);
  u16* sT0 = sT + wv * (2 * 16 * 72);
  u16* sT1 = sT0 + 16 * 72;
  const f32x4 zero4 = {0.f, 0.f, 0.f, 0.f};

  // ---- proj GEMM: A-frags straight from global (each row read once) ----
  bf16x8 paf[6];
  {
    const u16* arow = attnout + (size_t)(r0 + lrow) * 192;
    #pragma unroll
    for (int kc = 0; kc < 6; kc++)
      paf[kc] = *(const bf16x8*)(arow + kc * 32 + quad * 8);
  }
  f32x4 xr[12];
  #pragma unroll
  for (int ct = 0; ct < 12; ct++) {
    f32x4 acc = zero4;
    #pragma unroll
    for (int kc = 0; kc < 6; kc++) {
      bf16x8 b = *(const bf16x8*)(proj_wf + ((ct * 6 + kc) << 9) + ln8);
      acc = MFMA16(paf[kc], b, acc);
    }
    xr[ct] = acc;
  }
  #pragma unroll
  for (int ct = 0; ct < 12; ct++) {
    float pb = proj_b[ct * 16 + lrow];
    xr[ct][0] += pb; xr[ct][1] += pb; xr[ct][2] += pb; xr[ct][3] += pb;
  }

  // ---- LN2 fully in registers (reg index = row) ----
  f32x4 s1 = zero4, s2 = zero4;
  #pragma unroll
  for (int ct = 0; ct < 12; ct++) {
    s1 += xr[ct];
    s2 += xr[ct] * xr[ct];
  }
  #pragma unroll
  for (int m = 1; m <= 8; m <<= 1) {
    #pragma unroll
    for (int c = 0; c < 4; c++) {
      s1[c] += __shfl_xor(s1[c], m);
      s2[c] += __shfl_xor(s2[c], m);
    }
  }
  f32x4 mu, rs;
  #pragma unroll
  for (int c = 0; c < 4; c++) {
    mu[c] = s1[c] * (1.f / 192.f);
    float var = s2[c] * (1.f / 192.f) - mu[c] * mu[c];
    rs[c] = rsqrtf(var + 1e-5f);
  }
  // normalized bf16 -> wave-private sX
  #pragma unroll
  for (int ct = 0; ct < 12; ct++) {
    int col = ct * 16 + lrow;
    float gc = g[col], bc = bb[col];
    #pragma unroll
    for (int reg = 0; reg < 4; reg++)
      sXw[(quad * 4 + reg) * 200 + col] =
          f2bf((xr[ct][reg] - mu[reg]) * rs[reg] * gc + bc);
  }
  // A-frags for FC1, loaded once, held in registers for all 12 ch
  bf16x8 af[6];
  #pragma unroll
  for (int kc = 0; kc < 6; kc++)
    af[kc] = *(const bf16x8*)(sXw + lrow * 200 + kc * 32 + quad * 8);

  // ---- MLP: barrier-free ping-pong over ch chunks of 64 hidden ----
  f32x4 accO[12];
  #pragma unroll
  for (int t = 0; t < 12; t++) accO[t] = zero4;

  auto FC1 = [&](int ch, u16* dst) {
    f32x4 accT[4] = {zero4, zero4, zero4, zero4};
    #pragma unroll
    for (int kc = 0; kc < 6; kc++) {
      #pragma unroll
      for (int c2 = 0; c2 < 4; c2++) {
        bf16x8 b = *(const bf16x8*)(fc1_wf + (((ch * 4 + c2) * 6 + kc) << 9) + ln8);
        accT[c2] = MFMA16(af[kc], b, accT[c2]);
      }
    }
    #pragma unroll
    for (int c2 = 0; c2 < 4; c2++) {
      int col = c2 * 16 + lrow;
      float bias = fc1_b[ch * 64 + col];
      #pragma unroll
      for (int reg = 0; reg < 4; reg++) {
        float v = accT[c2][reg] + bias;
        dst[(quad * 4 + reg) * 72 + col] = f2bf(gelu_f(v));
      }
    }
  };
  auto FC2 = [&](int ch, const u16* src) {
    #pragma unroll
    for (int kc2 = 0; kc2 < 2; kc2++) {
      bf16x8 a = *(const bf16x8*)(src + lrow * 72 + kc2 * 32 + quad * 8);
      #pragma unroll
      for (int ct = 0; ct < 12; ct++) {
        bf16x8 b = *(const bf16x8*)(fc2_wf + (((ch * 2 + kc2) * 12 + ct) << 9) + ln8);
        accO[ct] = MFMA16(a, b, accO[ct]);
      }
    }
  };

  FC1(0, sT0);
  #pragma unroll
  for (int ch = 0; ch < 12; ch++) {
    u16* cur = (ch & 1) ? sT1 : sT0;
    u16* nxt = (ch & 1) ? sT0 : sT1;
    if (ch + 1 < 12) FC1(ch + 1, nxt);
    FC2(ch, cur);
  }

  // ---- residual + bias + reverse partition/roll scatter ----
  float fb[12];
  #pragma unroll
  for (int ct = 0; ct < 12; ct++) fb[ct] = fc2_b[ct * 16 + lrow];
  #pragma unroll
  for (int reg = 0; reg < 4; reg++) {
    int gr = r0 + quad * 4 + reg;
    int w = gr / 49, n = gr - w * 49;
    int b = w >> 6, wi = w & 63;
    int rr = n / 7;
    int hh = (wi >> 3) * 7 + rr + 3; if (hh >= 56) hh -= 56;
    int ww = (wi & 7) * 7 + (n - rr * 7) + 3; if (ww >= 56) ww -= 56;
    float* orow = out + ((size_t)b * 3136 + hh * 56 + ww) * 192;
    #pragma unroll
    for (int ct = 0; ct < 12; ct++)
      orow[ct * 16 + lrow] = xr[ct][reg] + accO[ct][reg] + fb[ct];
  }
}

extern "C" void kernel_launch(void* const* d_in, const int* in_sizes, int n_in,
                              void* d_out, int out_size, void* d_ws, size_t ws_size,
                              hipStream_t stream) {
  const float* x      = (const float*)d_in[0];
  const float* qkv_w  = (const float*)d_in[1];
  const float* qkv_b  = (const float*)d_in[2];
  const float* proj_w = (const float*)d_in[3];
  const float* proj_b = (const float*)d_in[4];
  const float* n1_g   = (const float*)d_in[5];
  const float* n1_b   = (const float*)d_in[6];
  const float* n2_g   = (const float*)d_in[7];
  const float* n2_b   = (const float*)d_in[8];
  const float* fc1_w  = (const float*)d_in[9];
  const float* fc1_b  = (const float*)d_in[10];
  const float* fc2_w  = (const float*)d_in[11];
  const float* fc2_b  = (const float*)d_in[12];
  float* out = (float*)d_out;
  char* ws = (char*)d_ws;

  // workspace layout (bytes)
  u16* qkvb    = (u16*)(ws + 0);            // 1024*6*4928*2 = 60,555,264
  u16* attnout = (u16*)(ws + 60555264);     // 38,535,168 -> ends 99,090,432
  u16* qkv_wf  = (u16*)(ws + 99090432);     // 221,184
  u16* proj_wf = (u16*)(ws + 99311616);     // 73,728
  u16* fc1_wf  = (u16*)(ws + 99385344);     // 294,912
  u16* fc2_wf  = (u16*)(ws + 99680256);     // 294,912 -> ends 99,975,168

  prep_weights<<<256, 256, 0, stream>>>(qkv_w, proj_w, fc1_w, fc2_w,
                                        qkv_wf, proj_wf, fc1_wf, fc2_wf);
  for (int hf = 0; hf < 2; hf++) {
    qkv_ln_kernel<<<392, 256, 0, stream>>>(x, n1_g, n1_b, qkv_wf, qkv_b,
                                           qkvb, hf * 50176, hf * 1024);
    attn2_kernel<<<1024, 384, 0, stream>>>(qkvb, attnout, hf * 1024);
  }
  projmlp_kernel<<<1568, 256, 0, stream>>>(attnout, proj_wf, proj_b,
                                           n2_g, n2_b, fc1_wf, fc1_b,
                                           fc2_wf, fc2_b, out);
}

// Round 4
// 454.452 us; speedup vs baseline: 1.6233x; 1.2956x over previous
//
#include <hip/hip_runtime.h>

typedef unsigned short u16;
typedef unsigned int u32;
typedef __bf16 bf16x8 __attribute__((ext_vector_type(8)));
typedef float f32x4 __attribute__((ext_vector_type(4)));

#define MFMA16(a,b,c) __builtin_amdgcn_mfma_f32_16x16x32_bf16((a),(b),(c),0,0,0)

__device__ __forceinline__ u16 f2bf(float x) {
  u32 u = __float_as_uint(x);
  u32 r = (u + 0x7fffu + ((u >> 16) & 1u)) >> 16;
  return (u16)r;
}

// branch-free erf-based GELU (A&S 7.1.26, |err| <= 1.5e-7)
__device__ __forceinline__ float gelu_f(float v) {
  float u = v * 0.70710678118654752f;
  float a = fabsf(u);
  float t = 1.f / (1.f + 0.3275911f * a);
  float p = t * (0.254829592f + t * (-0.284496736f + t * (1.421413741f +
            t * (-1.453152027f + t * 1.061405429f))));
  float e = __expf(-u * u);
  float er = 1.f - p * e;
  er = (u < 0.f) ? -er : er;
  return 0.5f * v * (1.f + er);
}

// ---------------- weight -> bf16 MFMA-fragment order ----------------
// Fragment f holds the B-operand tile (n-tile of 16, k-tile of 32) for
// mfma_f32_16x16x32_bf16: lane ln holds B[n = nt*16 + (ln&15)][k = kt*32 +
// (ln>>4)*8 + e], stored contiguously at wf[(f<<9) + (ln<<3) + e].
__global__ __launch_bounds__(256) void prep_weights(
    const float* __restrict__ qkv_w, const float* __restrict__ proj_w,
    const float* __restrict__ fc1_w, const float* __restrict__ fc2_w,
    u16* __restrict__ qkv_wf, u16* __restrict__ proj_wf,
    u16* __restrict__ fc1_wf, u16* __restrict__ fc2_wf) {
  int t0 = blockIdx.x * 256 + threadIdx.x;
  int stride = gridDim.x * 256;
  // qkv: f = ct*6 + kc, ct<36 (n over 576), kc<6 (k over 192)
  for (int i = t0; i < 36 * 6 * 512; i += stride) {
    int f = i >> 9, ln = (i >> 3) & 63, e = i & 7;
    int ct = f / 6, kc = f - ct * 6;
    int n = ct * 16 + (ln & 15), k = kc * 32 + (ln >> 4) * 8 + e;
    qkv_wf[i] = f2bf(qkv_w[k * 576 + n]);
  }
  // proj: f = ct*6 + kc, ct<12 (n over 192), kc<6
  for (int i = t0; i < 12 * 6 * 512; i += stride) {
    int f = i >> 9, ln = (i >> 3) & 63, e = i & 7;
    int ct = f / 6, kc = f - ct * 6;
    int n = ct * 16 + (ln & 15), k = kc * 32 + (ln >> 4) * 8 + e;
    proj_wf[i] = f2bf(proj_w[k * 192 + n]);
  }
  // fc1: f = ctg*6 + kc, ctg<48 (n over 768), kc<6 (k over 192)
  for (int i = t0; i < 48 * 6 * 512; i += stride) {
    int f = i >> 9, ln = (i >> 3) & 63, e = i & 7;
    int ctg = f / 6, kc = f - ctg * 6;
    int n = ctg * 16 + (ln & 15), k = kc * 32 + (ln >> 4) * 8 + e;
    fc1_wf[i] = f2bf(fc1_w[k * 768 + n]);
  }
  // fc2: f = g2*12 + ct, g2<24 (k over 768 in 32-steps), ct<12 (n over 192)
  for (int i = t0; i < 24 * 12 * 512; i += stride) {
    int f = i >> 9, ln = (i >> 3) & 63, e = i & 7;
    int g2 = f / 12, ct = f - g2 * 12;
    int n = ct * 16 + (ln & 15), k = g2 * 32 + (ln >> 4) * 8 + e;
    fc2_wf[i] = f2bf(fc2_w[k * 192 + n]);
  }
}

// ---------------- fused LN1(+shift/window gather) + QKV GEMM ----------------
__global__ __launch_bounds__(256) void qkv_ln_kernel(
    const float* __restrict__ x, const float* __restrict__ g,
    const float* __restrict__ bb,
    const u16* __restrict__ qkv_wf, const float* __restrict__ qkv_b,
    u16* __restrict__ qkvb, int rowbase, int wbase) {
  __shared__ __align__(16) u16 sA[128 * 200];
  const int tid = threadIdx.x;
  const int r0 = rowbase + blockIdx.x * 128;

  {
    int r = tid >> 1, half = tid & 1;
    int gr = r0 + r;
    int w = gr / 49, n = gr - w * 49;
    int b = w >> 6, wi = w & 63;
    int rr = n / 7, cc = n - rr * 7;
    int hh = (wi >> 3) * 7 + rr + 3; if (hh >= 56) hh -= 56;
    int ww = (wi & 7) * 7 + cc + 3; if (ww >= 56) ww -= 56;
    const float* src = x + ((size_t)b * 3136 + hh * 56 + ww) * 192 + half * 96;
    float s1 = 0.f, s2 = 0.f;
    #pragma unroll
    for (int i = 0; i < 24; i++) {
      float4 v = ((const float4*)src)[i];
      s1 += v.x + v.y + v.z + v.w;
      s2 += v.x * v.x + v.y * v.y + v.z * v.z + v.w * v.w;
    }
    s1 += __shfl_xor(s1, 1);
    s2 += __shfl_xor(s2, 1);
    float mu = s1 * (1.f / 192.f);
    float var = s2 * (1.f / 192.f) - mu * mu;
    float rs = rsqrtf(var + 1e-5f);
    u16* drow = sA + r * 200 + half * 96;
    #pragma unroll
    for (int i = 0; i < 24; i++) {
      float4 v = ((const float4*)src)[i];
      int c = half * 96 + i * 4;
      ushort4 o;
      o.x = f2bf((v.x - mu) * rs * g[c + 0] + bb[c + 0]);
      o.y = f2bf((v.y - mu) * rs * g[c + 1] + bb[c + 1]);
      o.z = f2bf((v.z - mu) * rs * g[c + 2] + bb[c + 2]);
      o.w = f2bf((v.w - mu) * rs * g[c + 3] + bb[c + 3]);
      *((ushort4*)(drow + i * 4)) = o;
    }
  }
  __syncthreads();

  const int wv = tid >> 6, ln = tid & 63, lrow = ln & 15, quad = ln >> 4;
  const int ln8 = ln << 3;

  u32 qkoff[8], voff[8];
  #pragma unroll
  for (int rt = 0; rt < 2; rt++) {
    #pragma unroll
    for (int reg = 0; reg < 4; reg++) {
      int grow = r0 + 32 * wv + 16 * rt + quad * 4 + reg;
      int w_ = grow / 49, n_ = grow - w_ * 49;
      u32 wb = (u32)(w_ - wbase) * 29568u;
      qkoff[rt * 4 + reg] = wb + (u32)n_ * 32u;
      voff[rt * 4 + reg] = wb + (u32)n_;
    }
  }

  for (int ct = 0; ct < 36; ct++) {
    f32x4 acc0 = (f32x4){0.f, 0.f, 0.f, 0.f};
    f32x4 acc1 = (f32x4){0.f, 0.f, 0.f, 0.f};
    #pragma unroll
    for (int kc = 0; kc < 6; kc++) {
      bf16x8 a0 = *(const bf16x8*)(sA + (32 * wv + lrow) * 200 + kc * 32 + quad * 8);
      bf16x8 a1 = *(const bf16x8*)(sA + (32 * wv + 16 + lrow) * 200 + kc * 32 + quad * 8);
      bf16x8 bw = *(const bf16x8*)(qkv_wf + ((ct * 6 + kc) << 9) + ln8);
      acc0 = MFMA16(a0, bw, acc0);
      acc1 = MFMA16(a1, bw, acc1);
    }
    int sec = ct / 12, ccc = ct - sec * 12;
    int head = ccc >> 1, d0 = (ccc & 1) * 16;
    int col = d0 + lrow;
    float bias = qkv_b[sec * 192 + head * 32 + col];
    u32 hoff = (u32)head * 4928u;
    if (sec < 2) {
      u32 coff = hoff + (u32)sec * 1568u + (u32)col;
      #pragma unroll
      for (int reg = 0; reg < 4; reg++) {
        qkvb[qkoff[reg] + coff] = f2bf(acc0[reg] + bias);
        qkvb[qkoff[4 + reg] + coff] = f2bf(acc1[reg] + bias);
      }
    } else {
      u32 coff = hoff + 3136u + (u32)col * 56u;
      #pragma unroll
      for (int reg = 0; reg < 4; reg++) {
        qkvb[voff[reg] + coff] = f2bf(acc0[reg] + bias);
        qkvb[voff[4 + reg] + coff] = f2bf(acc1[reg] + bias);
      }
    }
  }
}

// ---------------- window attention: 1 block/window, 1 wave/head ----------------
__global__ __launch_bounds__(384) void attn2_kernel(
    const u16* __restrict__ qkvb, u16* __restrict__ attnout, int wbase) {
  __shared__ __align__(16) u16 sP[6 * 64 * 72];
  const int tid = threadIdx.x;
  const int wv = tid >> 6;
  const int ln = tid & 63;
  const int lrow = ln & 15;
  const int quad = ln >> 4;
  const int wl = blockIdx.x;
  const int w = wbase + wl;
  const int wi = w & 63;
  const int wr = wi >> 3, wc = wi & 7;
  const u16* base = qkvb + (size_t)(wl * 6 + wv) * 4928;
  u16* sPw = sP + wv * (64 * 72);
  const f32x4 zero4 = {0.f, 0.f, 0.f, 0.f};

  bf16x8 kf[4];
  #pragma unroll
  for (int rt = 0; rt < 4; rt++)
    kf[rt] = *(const bf16x8*)(base + 1568 + (16 * rt + lrow) * 32 + quad * 8);
  f32x4 S[4][4];
  #pragma unroll
  for (int ct = 0; ct < 4; ct++) {
    bf16x8 qf = *(const bf16x8*)(base + (16 * ct + lrow) * 32 + quad * 8);
    #pragma unroll
    for (int rt = 0; rt < 4; rt++)
      S[rt][ct] = MFMA16(kf[rt], qf, zero4);
  }

  int hbn[4], wbn[4];
  #pragma unroll
  for (int ct = 0; ct < 4; ct++) {
    int n = 16 * ct + lrow;
    int rn = (n * 9363) >> 16;
    int cn = n - 7 * rn;
    hbn[ct] = (wr < 7) ? 0 : ((rn >= 4) ? 2 : 1);
    wbn[ct] = (wc < 7) ? 0 : ((cn >= 4) ? 2 : 1);
  }

  const float scale = 0.17677669529663687f;
  float mx[4] = {-1e30f, -1e30f, -1e30f, -1e30f};
  #pragma unroll
  for (int rt = 0; rt < 4; rt++) {
    #pragma unroll
    for (int reg = 0; reg < 4; reg++) {
      int m = 16 * rt + quad * 4 + reg;
      int rm = (m * 9363) >> 16;
      int cm = m - 7 * rm;
      int hbm = (wr < 7) ? 0 : ((rm >= 4) ? 2 : 1);
      int wbm = (wc < 7) ? 0 : ((cm >= 4) ? 2 : 1);
      bool padm = (m >= 49);
      #pragma unroll
      for (int ct = 0; ct < 4; ct++) {
        float sv = S[rt][ct][reg] * scale +
                   (((hbm != hbn[ct]) || (wbm != wbn[ct])) ? -100.f : 0.f);
        sv = padm ? -1e30f : sv;
        S[rt][ct][reg] = sv;
        mx[ct] = fmaxf(mx[ct], sv);
      }
    }
  }
  #pragma unroll
  for (int ct = 0; ct < 4; ct++) {
    mx[ct] = fmaxf(mx[ct], __shfl_xor(mx[ct], 16));
    mx[ct] = fmaxf(mx[ct], __shfl_xor(mx[ct], 32));
  }
  float sum[4] = {0.f, 0.f, 0.f, 0.f};
  #pragma unroll
  for (int rt = 0; rt < 4; rt++)
    #pragma unroll
    for (int reg = 0; reg < 4; reg++)
      #pragma unroll
      for (int ct = 0; ct < 4; ct++) {
        float e = __expf(S[rt][ct][reg] - mx[ct]);
        S[rt][ct][reg] = e;
        sum[ct] += e;
      }
  float inv[4];
  #pragma unroll
  for (int ct = 0; ct < 4; ct++) {
    sum[ct] += __shfl_xor(sum[ct], 16);
    sum[ct] += __shfl_xor(sum[ct], 32);
    inv[ct] = 1.f / sum[ct];
  }

  #pragma unroll
  for (int rt = 0; rt < 4; rt++) {
    #pragma unroll
    for (int ct = 0; ct < 4; ct++) {
      ushort4 o;
      o.x = f2bf(S[rt][ct][0] * inv[ct]);
      o.y = f2bf(S[rt][ct][1] * inv[ct]);
      o.z = f2bf(S[rt][ct][2] * inv[ct]);
      o.w = f2bf(S[rt][ct][3] * inv[ct]);
      *((ushort4*)(sPw + (16 * ct + lrow) * 72 + 16 * rt + quad * 4)) = o;
    }
  }

  f32x4 accO[4][2];
  #pragma unroll
  for (int rt = 0; rt < 4; rt++)
    #pragma unroll
    for (int cd = 0; cd < 2; cd++) accO[rt][cd] = zero4;
  #pragma unroll
  for (int kc = 0; kc < 2; kc++) {
    bf16x8 vf[2];
    #pragma unroll
    for (int cd = 0; cd < 2; cd++)
      vf[cd] = *(const bf16x8*)(base + 3136 + (16 * cd + lrow) * 56 + kc * 32 + quad * 8);
    #pragma unroll
    for (int rt = 0; rt < 4; rt++) {
      bf16x8 af = *(const bf16x8*)(sPw + (16 * rt + lrow) * 72 + kc * 32 + quad * 8);
      #pragma unroll
      for (int cd = 0; cd < 2; cd++)
        accO[rt][cd] = MFMA16(af, vf[cd], accO[rt][cd]);
    }
  }

  #pragma unroll
  for (int rt = 0; rt < 4; rt++) {
    #pragma unroll
    for (int reg = 0; reg < 4; reg++) {
      int n = 16 * rt + quad * 4 + reg;
      if (n < 49) {
        #pragma unroll
        for (int cd = 0; cd < 2; cd++)
          attnout[(size_t)(w * 49 + n) * 192 + wv * 32 + 16 * cd + lrow] =
              f2bf(accO[rt][cd][reg]);
      }
    }
  }
}

// ---------------- fused proj + LN2 + MLP + residual + scatter (cooperative) ----
// 256 threads, 64 rows/block. Column-split: wave wv owns output cols
// [48wv,48wv+48) of ALL 64 rows for proj, FC1 (16 hidden cols/chunk) and
// FC2. Every B-fragment is reused by 4 A-fragments (MFMA:load = 4:1) and
// FC1/FC2 weight reads have zero intra-block redundancy. Residual xr[4][3]
// and accO[4][3] live in registers end-to-end; LN2 stats cross wave via
// 2 KB LDS. Hidden tile double-buffered: ONE barrier per 64-hidden chunk.
// LDS 46 KB -> 3 blocks/CU; launch_bounds(256,3) -> 3 waves/SIMD.
__global__ __launch_bounds__(256, 3) void projmlp_kernel(
    const u16* __restrict__ attnout, const u16* __restrict__ proj_wf,
    const float* __restrict__ proj_b,
    const float* __restrict__ g, const float* __restrict__ bb,
    const u16* __restrict__ fc1_wf, const float* __restrict__ fc1_b,
    const u16* __restrict__ fc2_wf, const float* __restrict__ fc2_b,
    float* __restrict__ out) {
  __shared__ __align__(16) u16 sA[64 * 200];       // staged attnout, then LN2'd X
  __shared__ __align__(16) u16 sT[2 * 64 * 72];    // hidden tile, double buffer
  __shared__ __align__(16) float sStat[64 * 8];    // per-row (s1,s2) x 4 waves
  const int tid = threadIdx.x;
  const int wv = tid >> 6, ln = tid & 63, lrow = ln & 15, quad = ln >> 4;
  const int ln8 = ln << 3;
  const int r0 = blockIdx.x * 64;
  const f32x4 zero4 = {0.f, 0.f, 0.f, 0.f};

  // ---- stage attnout rows -> sA (bf16, stride 200) ----
  {
    const u32* src = (const u32*)(attnout + (size_t)r0 * 192);
    u32* dst = (u32*)sA;
    #pragma unroll
    for (int i = 0; i < 24; i++) {
      int idx = tid + i * 256;                 // 64*96 dwords
      int r = idx / 96, c = idx - r * 96;
      dst[r * 100 + c] = src[idx];
    }
  }
  __syncthreads();   // B1: sA staged

  // ---- proj GEMM: xr[rt][ct] = rows 16rt+4quad+reg, cols 48wv+16ct+lrow ----
  f32x4 xr[4][3];
  #pragma unroll
  for (int rt = 0; rt < 4; rt++)
    #pragma unroll
    for (int ct = 0; ct < 3; ct++) xr[rt][ct] = zero4;
  #pragma unroll
  for (int kc = 0; kc < 6; kc++) {
    bf16x8 af[4];
    #pragma unroll
    for (int rt = 0; rt < 4; rt++)
      af[rt] = *(const bf16x8*)(sA + (16 * rt + lrow) * 200 + kc * 32 + quad * 8);
    #pragma unroll
    for (int ct = 0; ct < 3; ct++) {
      bf16x8 b = *(const bf16x8*)(proj_wf + (((wv * 3 + ct) * 6 + kc) << 9) + ln8);
      #pragma unroll
      for (int rt = 0; rt < 4; rt++)
        xr[rt][ct] = MFMA16(af[rt], b, xr[rt][ct]);
    }
  }
  #pragma unroll
  for (int ct = 0; ct < 3; ct++) {
    float pb = proj_b[wv * 48 + ct * 16 + lrow];
    #pragma unroll
    for (int rt = 0; rt < 4; rt++) {
      xr[rt][ct][0] += pb; xr[rt][ct][1] += pb;
      xr[rt][ct][2] += pb; xr[rt][ct][3] += pb;
    }
  }

  // ---- LN2 stats: partial (48 cols) per row, exchange via LDS ----
  {
    float ps1[4][4], ps2[4][4];
    #pragma unroll
    for (int rt = 0; rt < 4; rt++)
      #pragma unroll
      for (int reg = 0; reg < 4; reg++) {
        float a = xr[rt][0][reg] + xr[rt][1][reg] + xr[rt][2][reg];
        float b = xr[rt][0][reg] * xr[rt][0][reg] +
                  xr[rt][1][reg] * xr[rt][1][reg] +
                  xr[rt][2][reg] * xr[rt][2][reg];
        ps1[rt][reg] = a; ps2[rt][reg] = b;
      }
    #pragma unroll
    for (int m = 1; m <= 8; m <<= 1)
      #pragma unroll
      for (int rt = 0; rt < 4; rt++)
        #pragma unroll
        for (int reg = 0; reg < 4; reg++) {
          ps1[rt][reg] += __shfl_xor(ps1[rt][reg], m);
          ps2[rt][reg] += __shfl_xor(ps2[rt][reg], m);
        }
    if (lrow == 0) {
      #pragma unroll
      for (int rt = 0; rt < 4; rt++)
        #pragma unroll
        for (int reg = 0; reg < 4; reg++) {
          int row = 16 * rt + 4 * quad + reg;
          *(float2*)&sStat[row * 8 + wv * 2] =
              make_float2(ps1[rt][reg], ps2[rt][reg]);
        }
    }
  }
  __syncthreads();   // B2: stats ready AND all proj ds_reads of sA done

  // ---- finish LN2, write normalized bf16 back into sA (overwrite) ----
  {
    float gc[3], bc[3];
    #pragma unroll
    for (int ct = 0; ct < 3; ct++) {
      int col = wv * 48 + ct * 16 + lrow;
      gc[ct] = g[col]; bc[ct] = bb[col];
    }
    #pragma unroll
    for (int rt = 0; rt < 4; rt++) {
      float mu_[4], rs_[4];
      #pragma unroll
      for (int reg = 0; reg < 4; reg++) {
        int row = 16 * rt + 4 * quad + reg;
        f32x4 q0 = *(const f32x4*)&sStat[row * 8];
        f32x4 q1 = *(const f32x4*)&sStat[row * 8 + 4];
        float s1 = q0[0] + q0[2] + q1[0] + q1[2];
        float s2 = q0[1] + q0[3] + q1[1] + q1[3];
        float mu = s1 * (1.f / 192.f);
        float var = s2 * (1.f / 192.f) - mu * mu;
        mu_[reg] = mu; rs_[reg] = rsqrtf(var + 1e-5f);
      }
      #pragma unroll
      for (int ct = 0; ct < 3; ct++) {
        int col = wv * 48 + ct * 16 + lrow;
        #pragma unroll
        for (int reg = 0; reg < 4; reg++) {
          int row = 16 * rt + 4 * quad + reg;
          sA[row * 200 + col] =
              f2bf((xr[rt][ct][reg] - mu_[reg]) * rs_[reg] * gc[ct] + bc[ct]);
        }
      }
    }
  }
  __syncthreads();   // B3: normalized X ready

  // ---- MLP: 12 chunks of 64 hidden, double-buffered sT, 1 barrier/chunk ----
  f32x4 accO[4][3];
  #pragma unroll
  for (int rt = 0; rt < 4; rt++)
    #pragma unroll
    for (int ct = 0; ct < 3; ct++) accO[rt][ct] = zero4;

  auto FC1 = [&](int ch, u16* dst) {
    f32x4 accT[4] = {zero4, zero4, zero4, zero4};
    #pragma unroll
    for (int kc = 0; kc < 6; kc++) {
      bf16x8 af[4];
      #pragma unroll
      for (int rt = 0; rt < 4; rt++)
        af[rt] = *(const bf16x8*)(sA + (16 * rt + lrow) * 200 + kc * 32 + quad * 8);
      bf16x8 b = *(const bf16x8*)(fc1_wf + (((ch * 4 + wv) * 6 + kc) << 9) + ln8);
      #pragma unroll
      for (int rt = 0; rt < 4; rt++)
        accT[rt] = MFMA16(af[rt], b, accT[rt]);
    }
    float b1 = fc1_b[ch * 64 + wv * 16 + lrow];
    #pragma unroll
    for (int rt = 0; rt < 4; rt++)
      #pragma unroll
      for (int reg = 0; reg < 4; reg++) {
        float v = accT[rt][reg] + b1;
        dst[(16 * rt + 4 * quad + reg) * 72 + wv * 16 + lrow] = f2bf(gelu_f(v));
      }
  };
  auto FC2 = [&](int ch, const u16* src) {
    #pragma unroll
    for (int kc2 = 0; kc2 < 2; kc2++) {
      bf16x8 ta[4];
      #pragma unroll
      for (int rt = 0; rt < 4; rt++)
        ta[rt] = *(const bf16x8*)(src + (16 * rt + lrow) * 72 + kc2 * 32 + quad * 8);
      #pragma unroll
      for (int ct = 0; ct < 3; ct++) {
        bf16x8 b = *(const bf16x8*)(fc2_wf +
            (((ch * 2 + kc2) * 12 + wv * 3 + ct) << 9) + ln8);
        #pragma unroll
        for (int rt = 0; rt < 4; rt++)
          accO[rt][ct] = MFMA16(ta[rt], b, accO[rt][ct]);
      }
    }
  };

  FC1(0, sT);
  __syncthreads();   // B4: T0 ready
  for (int ch = 0; ch < 12; ch++) {
    u16* cur = sT + (ch & 1) * (64 * 72);
    u16* nxt = sT + ((ch + 1) & 1) * (64 * 72);
    if (ch < 11) FC1(ch + 1, nxt);
    FC2(ch, cur);
    __syncthreads();  // protects nxt-read (ch+1) and cur-overwrite (ch+2)
  }

  // ---- residual + bias + reverse partition/roll scatter ----
  float fb[3];
  #pragma unroll
  for (int ct = 0; ct < 3; ct++) fb[ct] = fc2_b[wv * 48 + ct * 16 + lrow];
  #pragma unroll
  for (int rt = 0; rt < 4; rt++) {
    #pragma unroll
    for (int reg = 0; reg < 4; reg++) {
      int gr = r0 + 16 * rt + 4 * quad + reg;
      int w = gr / 49, n = gr - w * 49;
      int b = w >> 6, wi = w & 63;
      int rr = n / 7;
      int hh = (wi >> 3) * 7 + rr + 3; if (hh >= 56) hh -= 56;
      int ww = (wi & 7) * 7 + (n - rr * 7) + 3; if (ww >= 56) ww -= 56;
      float* orow = out + ((size_t)b * 3136 + hh * 56 + ww) * 192;
      #pragma unroll
      for (int ct = 0; ct < 3; ct++)
        orow[wv * 48 + ct * 16 + lrow] =
            xr[rt][ct][reg] + accO[rt][ct][reg] + fb[ct];
    }
  }
}

extern "C" void kernel_launch(void* const* d_in, const int* in_sizes, int n_in,
                              void* d_out, int out_size, void* d_ws, size_t ws_size,
                              hipStream_t stream) {
  const float* x      = (const float*)d_in[0];
  const float* qkv_w  = (const float*)d_in[1];
  const float* qkv_b  = (const float*)d_in[2];
  const float* proj_w = (const float*)d_in[3];
  const float* proj_b = (const float*)d_in[4];
  const float* n1_g   = (const float*)d_in[5];
  const float* n1_b   = (const float*)d_in[6];
  const float* n2_g   = (const float*)d_in[7];
  const float* n2_b   = (const float*)d_in[8];
  const float* fc1_w  = (const float*)d_in[9];
  const float* fc1_b  = (const float*)d_in[10];
  const float* fc2_w  = (const float*)d_in[11];
  const float* fc2_b  = (const float*)d_in[12];
  float* out = (float*)d_out;
  char* ws = (char*)d_ws;

  // workspace layout (bytes)
  u16* qkvb    = (u16*)(ws + 0);            // 1024*6*4928*2 = 60,555,264
  u16* attnout = (u16*)(ws + 60555264);     // 38,535,168 -> ends 99,090,432
  u16* qkv_wf  = (u16*)(ws + 99090432);     // 221,184
  u16* proj_wf = (u16*)(ws + 99311616);     // 73,728
  u16* fc1_wf  = (u16*)(ws + 99385344);     // 294,912
  u16* fc2_wf  = (u16*)(ws + 99680256);     // 294,912 -> ends 99,975,168

  prep_weights<<<256, 256, 0, stream>>>(qkv_w, proj_w, fc1_w, fc2_w,
                                        qkv_wf, proj_wf, fc1_wf, fc2_wf);
  for (int hf = 0; hf < 2; hf++) {
    qkv_ln_kernel<<<392, 256, 0, stream>>>(x, n1_g, n1_b, qkv_wf, qkv_b,
                                           qkvb, hf * 50176, hf * 1024);
    attn2_kernel<<<1024, 384, 0, stream>>>(qkvb, attnout, hf * 1024);
  }
  projmlp_kernel<<<1568, 256, 0, stream>>>(attnout, proj_wf, proj_b,
                                           n2_g, n2_b, fc1_wf, fc1_b,
                                           fc2_wf, fc2_b, out);
}